// Round 1
// baseline (1412.168 us; speedup 1.0000x reference)
//
#include <hip/hip_runtime.h>
#include <cstdint>
#include <cstddef>

// VQ-VAE vector quantizer forward, MI355X.
// B=65536 rows, K=4096 codes, D=256.
// Outputs (flat float32): z_q_st[B*D] | vq_loss | perplexity | indices[B] | diversity_loss

#define NROWS     65536
#define NCODES    4096
#define DDIM      256
#define CAND_CAP  24
#define MARGIN    0.5f

typedef _Float16 half8 __attribute__((ext_vector_type(8)));
typedef _Float16 half4 __attribute__((ext_vector_type(4)));
typedef float    f32x4 __attribute__((ext_vector_type(4)));

// ---- workspace layout (bytes) ----
#define WS_SPART    0u          // 512*4096*4   = 8388608   (zeroed)
#define WS_CANDCNT  8388608u    // 65536*4      = 262144    (zeroed)
#define WS_BINCNT   8650752u    // 4096*4       = 16384     (zeroed)
#define WS_MSE      8667136u    // 64           (zeroed)
#define WS_ZERO_END 8667200u
#define WS_EF16     8667200u    // 4096*256*2   = 2097152
#define WS_ZZ       10764352u   // 65536*4      = 262144
#define WS_EE       11026496u   // 4096*4       = 16384
#define WS_ROWM     11042880u   // 65536*4      = 262144
#define WS_ROWZ     11305024u   // 65536*4      = 262144
#define WS_CANDIDX  11567168u   // 65536*24*4   = 6291456
#define WS_TE       17858624u   // 4096*8       = 32768
#define WS_TP       17891392u   // 4096*8       = 32768
#define WS_END      17924160u

// ---------------- prep: fp32 row-matrix -> fp16 copy + fp64 row norms ----------------
// One wave per row (4 rows / 256-thread block).
__global__ __launch_bounds__(256)
void prep_kernel(const float* __restrict__ src, _Float16* __restrict__ dst,
                 float* __restrict__ norms)
{
    const int tid = threadIdx.x;
    const int w = tid >> 6, l = tid & 63;
    const int row = blockIdx.x * 4 + w;
    const float4 v = *(const float4*)(src + (size_t)row * DDIM + l * 4);
    half4 h;
    h[0] = (_Float16)v.x; h[1] = (_Float16)v.y;
    h[2] = (_Float16)v.z; h[3] = (_Float16)v.w;
    *(half4*)(dst + (size_t)row * DDIM + l * 4) = h;
    double s = (double)v.x * v.x + (double)v.y * v.y
             + (double)v.z * v.z + (double)v.w * v.w;
#pragma unroll
    for (int off = 1; off < 64; off <<= 1) s += __shfl_xor(s, off, 64);
    if (l == 0) norms[row] = (float)s;
}

// ---------------- fused distance GEMM sweep ----------------
// Tile: 128 rows x 128 codes, K=256 in 4 steps of 64. 4 waves; wave w owns rows
// w*32..w*32+31 across all 128 tile cols, so per-row reductions are in-wave.
// MODE 0: per-row running min m and flash Z = sum exp(m - d).  MODE 1: identical
// d values; accumulate exp(m-d)/Z into LDS S[4096]; append argmin candidates.
template<int MODE>
__global__ __launch_bounds__(256, 2)
void sweep_kernel(const _Float16* __restrict__ zf, const _Float16* __restrict__ ef,
                  const float* __restrict__ zz, const float* __restrict__ ee,
                  float* __restrict__ rowM, float* __restrict__ rowZ,
                  float* __restrict__ Spart, int* __restrict__ cand_cnt,
                  int* __restrict__ cand_idx)
{
    // 72-element (144B) pitch: 16B-aligned rows for b128 LDS ops, bank-stride 36%32=4
    // -> worst 2-way conflict (free).
    __shared__ _Float16 Al[128][72];
    __shared__ _Float16 Bl[128][72];
    __shared__ float Sl[NCODES];      // MODE 1 accumulator
    __shared__ float zzl[128];
    __shared__ float eel[128];
    __shared__ float rml[128];
    __shared__ float rizl[128];

    const int tid = threadIdx.x;
    const int w  = tid >> 6;
    const int l  = tid & 63;
    const int lg = l >> 4;   // lane group 0..3
    const int lc = l & 15;   // lane col
    const int row0 = blockIdx.x * 128;

    for (int i = tid; i < 128; i += 256) {
        zzl[i] = zz[row0 + i];
        if (MODE == 1) {
            rml[i]  = rowM[row0 + i];
            rizl[i] = 1.0f / rowZ[row0 + i];
        }
    }
    if (MODE == 1)
        for (int i = tid; i < NCODES; i += 256) Sl[i] = 0.0f;

    float runM[8], runZ[8];
#pragma unroll
    for (int i = 0; i < 8; ++i) { runM[i] = 1e30f; runZ[i] = 0.0f; }

    for (int nt = 0; nt < 32; ++nt) {
        f32x4 acc[2][8];
#pragma unroll
        for (int fr = 0; fr < 2; ++fr)
#pragma unroll
            for (int cf = 0; cf < 8; ++cf) acc[fr][cf] = (f32x4){0.f, 0.f, 0.f, 0.f};

        for (int ks = 0; ks < 4; ++ks) {
            __syncthreads();
#pragma unroll
            for (int i = 0; i < 4; ++i) {     // stage A(z) and B(e^T) 128x64 tiles
                int c2 = tid + i * 256;
                int r = c2 >> 3, c8 = c2 & 7;
                const uint4 av = *(const uint4*)(zf + (size_t)(row0 + r) * DDIM + ks * 64 + c8 * 8);
                *(uint4*)&Al[r][c8 * 8] = av;
                const uint4 bv = *(const uint4*)(ef + (size_t)(nt * 128 + r) * DDIM + ks * 64 + c8 * 8);
                *(uint4*)&Bl[r][c8 * 8] = bv;
            }
            if (ks == 0 && tid < 128) eel[tid] = ee[nt * 128 + tid];
            __syncthreads();
#pragma unroll
            for (int kk = 0; kk < 2; ++kk) {
                const half8 a0 = *(const half8*)&Al[w * 32 + lc][kk * 32 + lg * 8];
                const half8 a1 = *(const half8*)&Al[w * 32 + 16 + lc][kk * 32 + lg * 8];
#pragma unroll
                for (int cf = 0; cf < 8; ++cf) {
                    const half8 b = *(const half8*)&Bl[cf * 16 + lc][kk * 32 + lg * 8];
                    acc[0][cf] = __builtin_amdgcn_mfma_f32_16x16x32_f16(a0, b, acc[0][cf], 0, 0, 0);
                    acc[1][cf] = __builtin_amdgcn_mfma_f32_16x16x32_f16(a1, b, acc[1][cf], 0, 0, 0);
                }
            }
        }

        // ---- epilogue: d = zz + ee - 2*dot.  C frag: col = lc, row = lg*4+reg ----
        if (MODE == 0) {
#pragma unroll
            for (int fr = 0; fr < 2; ++fr)
#pragma unroll
            for (int reg = 0; reg < 4; ++reg) {
                const int rl = w * 32 + fr * 16 + lg * 4 + reg;
                const float zr = zzl[rl];
                float dv[8], mloc = 1e30f;
#pragma unroll
                for (int cf = 0; cf < 8; ++cf) {
                    const float d = fmaf(-2.0f, acc[fr][cf][reg], zr + eel[cf * 16 + lc]);
                    dv[cf] = d;
                    mloc = fminf(mloc, d);
                }
#pragma unroll
                for (int off = 1; off < 16; off <<= 1)
                    mloc = fminf(mloc, __shfl_xor(mloc, off, 64));
                const int ri = fr * 4 + reg;
                const float nM = fminf(runM[ri], mloc);
                float s = 0.0f;
#pragma unroll
                for (int cf = 0; cf < 8; ++cf) s += __expf(nM - dv[cf]);
#pragma unroll
                for (int off = 1; off < 16; off <<= 1)
                    s += __shfl_xor(s, off, 64);
                runZ[ri] = runZ[ri] * __expf(nM - runM[ri]) + s;
                runM[ri] = nM;
            }
        } else {
            float sp[8];
#pragma unroll
            for (int cf = 0; cf < 8; ++cf) sp[cf] = 0.0f;
#pragma unroll
            for (int fr = 0; fr < 2; ++fr)
#pragma unroll
            for (int reg = 0; reg < 4; ++reg) {
                const int rl = w * 32 + fr * 16 + lg * 4 + reg;
                const float m = rml[rl], iz = rizl[rl], zr = zzl[rl];
#pragma unroll
                for (int cf = 0; cf < 8; ++cf) {
                    const float d = fmaf(-2.0f, acc[fr][cf][reg], zr + eel[cf * 16 + lc]);
                    sp[cf] += __expf(m - d) * iz;
                    if (d <= m + MARGIN) {   // includes argmin: d values bitwise == sweep A
                        const int rg_ = row0 + rl;
                        const int slot = atomicAdd(&cand_cnt[rg_], 1);
                        if (slot < CAND_CAP)
                            cand_idx[rg_ * CAND_CAP + slot] = nt * 128 + cf * 16 + lc;
                    }
                }
            }
#pragma unroll
            for (int cf = 0; cf < 8; ++cf) {
                float v = sp[cf];
                v += __shfl_xor(v, 16, 64);
                v += __shfl_xor(v, 32, 64);
                if (l < 16) atomicAdd(&Sl[nt * 128 + cf * 16 + l], v);
            }
        }
    }

    if (MODE == 0) {
        if (lc == 0) {
#pragma unroll
            for (int fr = 0; fr < 2; ++fr)
#pragma unroll
            for (int reg = 0; reg < 4; ++reg) {
                const int rl = w * 32 + fr * 16 + lg * 4 + reg;
                rowM[row0 + rl] = runM[fr * 4 + reg];
                rowZ[row0 + rl] = runZ[fr * 4 + reg];
            }
        }
    } else {
        __syncthreads();
        for (int i = tid; i < NCODES; i += 256)
            Spart[(size_t)blockIdx.x * NCODES + i] = Sl[i];
    }
}

// ---------------- refine: exact fp64 argmin over candidates ----------------
__global__ __launch_bounds__(256)
void refine_kernel(const float* __restrict__ z, const float* __restrict__ emb,
                   const int* __restrict__ cand_cnt, const int* __restrict__ cand_idx,
                   float* __restrict__ out_zq, float* __restrict__ out_idx,
                   unsigned int* __restrict__ bincnt, double* __restrict__ mse_acc)
{
    const int tid = threadIdx.x;
    const int w = tid >> 6, l = tid & 63;
    const int row = blockIdx.x * 4 + w;
    const float4 zv = *(const float4*)(z + (size_t)row * DDIM + l * 4);
    const double z0 = zv.x, z1 = zv.y, z2 = zv.z, z3 = zv.w;
    const int craw = cand_cnt[row];
    const int cnt = craw < 1 ? 1 : (craw > CAND_CAP ? CAND_CAP : craw);
    double dmin = 1e300; int kmin = 0;
    for (int c = 0; c < cnt; ++c) {
        int k = (craw < 1) ? 0 : cand_idx[row * CAND_CAP + c];
        k &= (NCODES - 1);
        const float4 ev = *(const float4*)(emb + (size_t)k * DDIM + l * 4);
        const double t0 = z0 - ev.x, t1 = z1 - ev.y, t2 = z2 - ev.z, t3 = z3 - ev.w;
        double s = t0 * t0 + t1 * t1 + t2 * t2 + t3 * t3;
#pragma unroll
        for (int off = 1; off < 64; off <<= 1) s += __shfl_xor(s, off, 64);
        if (s < dmin || (s == dmin && k < kmin)) { dmin = s; kmin = k; }
    }
    const float4 bv = *(const float4*)(emb + (size_t)kmin * DDIM + l * 4);
    *(float4*)(out_zq + (size_t)row * DDIM + l * 4) = bv;   // z + sg(zq - z) == zq
    if (l == 0) {
        out_idx[row] = (float)kmin;
        atomicAdd(&bincnt[kmin], 1u);
        atomicAdd(mse_acc, dmin);                            // dmin == ||z - zq||^2
    }
}

// ---------------- reductions ----------------
__global__ __launch_bounds__(256)
void reduce1_kernel(const float* __restrict__ Spart, const unsigned int* __restrict__ bincnt,
                    double* __restrict__ te, double* __restrict__ tp)
{
    const int k = blockIdx.x * 256 + threadIdx.x;   // grid 16 -> k < 4096
    double s = 0.0;
    for (int wg = 0; wg < 512; ++wg) s += (double)Spart[(size_t)wg * NCODES + k];
    const double avg = s * (1.0 / 65536.0);
    te[k] = avg * log(avg + 1e-10);
    const double ap = (double)bincnt[k] * (1.0 / 65536.0);
    tp[k] = ap * log(ap + 1e-10);
}

__global__ __launch_bounds__(256)
void reduce2_kernel(const double* __restrict__ te, const double* __restrict__ tp,
                    const double* __restrict__ mse_acc, float* __restrict__ out)
{
    __shared__ double sa[256], sb[256];
    const int tid = threadIdx.x;
    double a = 0.0, b = 0.0;
    for (int i = tid; i < NCODES; i += 256) { a += te[i]; b += tp[i]; }
    sa[tid] = a; sb[tid] = b;
    __syncthreads();
    for (int s = 128; s > 0; s >>= 1) {
        if (tid < s) { sa[tid] += sa[tid + s]; sb[tid] += sb[tid + s]; }
        __syncthreads();
    }
    if (tid == 0) {
        const double entropy    = -sa[0];
        const double diversity  = log(4096.0) - entropy;
        const double perplexity = exp(-sb[0]);
        const double mse        = mse_acc[0] * (1.0 / 16777216.0);
        const double vq         = 1.25 * mse + 0.1 * diversity;  // 0.25*c + e + 0.1*d, c==e
        out[16777216] = (float)vq;
        out[16777217] = (float)perplexity;
        out[16842754] = (float)diversity;
    }
}

extern "C" void kernel_launch(void* const* d_in, const int* in_sizes, int n_in,
                              void* d_out, int out_size, void* d_ws, size_t ws_size,
                              hipStream_t stream)
{
    const float* z   = (const float*)d_in[0];
    const float* emb = (const float*)d_in[1];
    float* out = (float*)d_out;
    char* ws = (char*)d_ws;
    if (ws_size < (size_t)WS_END) return;   // need ~18 MB scratch

    float*        Spart    = (float*)(ws + WS_SPART);
    int*          cand_cnt = (int*)(ws + WS_CANDCNT);
    unsigned int* bincnt   = (unsigned int*)(ws + WS_BINCNT);
    double*       mse_acc  = (double*)(ws + WS_MSE);
    _Float16*     ef16     = (_Float16*)(ws + WS_EF16);
    float*        zz       = (float*)(ws + WS_ZZ);
    float*        ee       = (float*)(ws + WS_EE);
    float*        rowM     = (float*)(ws + WS_ROWM);
    float*        rowZ     = (float*)(ws + WS_ROWZ);
    int*          cand_idx = (int*)(ws + WS_CANDIDX);
    double*       te       = (double*)(ws + WS_TE);
    double*       tp       = (double*)(ws + WS_TP);

    // z_f16 (32 MB) lives in the d_out z_q region; refine overwrites it at the end.
    _Float16* zf16 = (_Float16*)d_out;

    hipMemsetAsync(d_ws, 0, WS_ZERO_END, stream);
    hipLaunchKernelGGL(prep_kernel, dim3(NROWS / 4), dim3(256), 0, stream, z, zf16, zz);
    hipLaunchKernelGGL(prep_kernel, dim3(NCODES / 4), dim3(256), 0, stream, emb, ef16, ee);
    hipLaunchKernelGGL((sweep_kernel<0>), dim3(NROWS / 128), dim3(256), 0, stream,
                       zf16, ef16, zz, ee, rowM, rowZ, Spart, cand_cnt, cand_idx);
    hipLaunchKernelGGL((sweep_kernel<1>), dim3(NROWS / 128), dim3(256), 0, stream,
                       zf16, ef16, zz, ee, rowM, rowZ, Spart, cand_cnt, cand_idx);
    hipLaunchKernelGGL(refine_kernel, dim3(NROWS / 4), dim3(256), 0, stream,
                       z, emb, cand_cnt, cand_idx, out, out + 16777218, bincnt, mse_acc);
    hipLaunchKernelGGL(reduce1_kernel, dim3(16), dim3(256), 0, stream, Spart, bincnt, te, tp);
    hipLaunchKernelGGL(reduce2_kernel, dim3(1), dim3(256), 0, stream, te, tp, mse_acc, out);
}

// Round 2
// 633.929 us; speedup vs baseline: 2.2276x; 2.2276x over previous
//
#include <hip/hip_runtime.h>
#include <cstdint>
#include <cstddef>

// VQ-VAE vector quantizer forward, MI355X.
// B=65536 rows, K=4096 codes, D=256.
// Outputs (flat float32): z_q_st[B*D] | vq_loss | perplexity | indices[B] | diversity_loss

#define NROWS     65536
#define NCODES    4096
#define DDIM      256
#define CAND_CAP  24
#define MARGIN    0.5f

typedef _Float16 half8 __attribute__((ext_vector_type(8)));
typedef _Float16 half4 __attribute__((ext_vector_type(4)));
typedef float    f32x4 __attribute__((ext_vector_type(4)));

// ---- workspace layout (bytes) ----
#define WS_CANDCNT  0u          // 65536*4      = 262144    (zeroed)
#define WS_BINCNT   262144u     // 4096*4       = 16384     (zeroed)
#define WS_ZERO_END 278528u
#define WS_SPART    278528u     // 512*4096*4   = 8388608   (fully overwritten by sweep<1>)
#define WS_EF16     8667136u    // 4096*256*2   = 2097152
#define WS_ZZ       10764288u   // 65536*4      = 262144
#define WS_EE       11026432u   // 4096*4       = 16384
#define WS_ROWM     11042816u   // 65536*4      = 262144   (aliased as rowD after sweep<1>)
#define WS_ROWZ     11304960u   // 65536*4      = 262144
#define WS_CANDIDX  11567104u   // 65536*24*4   = 6291456  (aliased as tm[4096] dbl after refine)
#define WS_TE       17858560u   // 4096*8       = 32768
#define WS_TP       17891328u   // 4096*8       = 32768
#define WS_END      17924096u

// ---------------- prep: fp32 row-matrix -> fp16 copy + fp64 row norms ----------------
// One wave per row (4 rows / 256-thread block).
__global__ __launch_bounds__(256)
void prep_kernel(const float* __restrict__ src, _Float16* __restrict__ dst,
                 float* __restrict__ norms)
{
    const int tid = threadIdx.x;
    const int w = tid >> 6, l = tid & 63;
    const int row = blockIdx.x * 4 + w;
    const float4 v = *(const float4*)(src + (size_t)row * DDIM + l * 4);
    half4 h;
    h[0] = (_Float16)v.x; h[1] = (_Float16)v.y;
    h[2] = (_Float16)v.z; h[3] = (_Float16)v.w;
    *(half4*)(dst + (size_t)row * DDIM + l * 4) = h;
    double s = (double)v.x * v.x + (double)v.y * v.y
             + (double)v.z * v.z + (double)v.w * v.w;
#pragma unroll
    for (int off = 1; off < 64; off <<= 1) s += __shfl_xor(s, off, 64);
    if (l == 0) norms[row] = (float)s;
}

// ---------------- fused distance GEMM sweep ----------------
// Tile: 128 rows x 128 codes, K=256 in 4 steps of 64. 4 waves; wave w owns rows
// w*32..w*32+31 across all 128 tile cols, so per-row reductions are in-wave.
// MODE 0: per-row running min m and flash Z = sum exp(m - d).  MODE 1: identical
// d values; accumulate exp(m-d)/Z into LDS S[4096]; append argmin candidates.
template<int MODE>
__global__ __launch_bounds__(256, 2)
void sweep_kernel(const _Float16* __restrict__ zf, const _Float16* __restrict__ ef,
                  const float* __restrict__ zz, const float* __restrict__ ee,
                  float* __restrict__ rowM, float* __restrict__ rowZ,
                  float* __restrict__ Spart, int* __restrict__ cand_cnt,
                  int* __restrict__ cand_idx)
{
    // 72-element (144B) pitch: 16B-aligned rows for b128 LDS ops, bank-stride 36%32=4
    // -> worst 2-way conflict (free).
    __shared__ _Float16 Al[128][72];
    __shared__ _Float16 Bl[128][72];
    __shared__ float Sl[NCODES];      // MODE 1 accumulator
    __shared__ float zzl[128];
    __shared__ float eel[128];
    __shared__ float rml[128];
    __shared__ float rizl[128];

    const int tid = threadIdx.x;
    const int w  = tid >> 6;
    const int l  = tid & 63;
    const int lg = l >> 4;   // lane group 0..3
    const int lc = l & 15;   // lane col
    const int row0 = blockIdx.x * 128;

    for (int i = tid; i < 128; i += 256) {
        zzl[i] = zz[row0 + i];
        if (MODE == 1) {
            rml[i]  = rowM[row0 + i];
            rizl[i] = 1.0f / rowZ[row0 + i];
        }
    }
    if (MODE == 1)
        for (int i = tid; i < NCODES; i += 256) Sl[i] = 0.0f;

    float runM[8], runZ[8];
#pragma unroll
    for (int i = 0; i < 8; ++i) { runM[i] = 1e30f; runZ[i] = 0.0f; }

    for (int nt = 0; nt < 32; ++nt) {
        f32x4 acc[2][8];
#pragma unroll
        for (int fr = 0; fr < 2; ++fr)
#pragma unroll
            for (int cf = 0; cf < 8; ++cf) acc[fr][cf] = (f32x4){0.f, 0.f, 0.f, 0.f};

        for (int ks = 0; ks < 4; ++ks) {
            __syncthreads();
#pragma unroll
            for (int i = 0; i < 4; ++i) {     // stage A(z) and B(e^T) 128x64 tiles
                int c2 = tid + i * 256;
                int r = c2 >> 3, c8 = c2 & 7;
                const uint4 av = *(const uint4*)(zf + (size_t)(row0 + r) * DDIM + ks * 64 + c8 * 8);
                *(uint4*)&Al[r][c8 * 8] = av;
                const uint4 bv = *(const uint4*)(ef + (size_t)(nt * 128 + r) * DDIM + ks * 64 + c8 * 8);
                *(uint4*)&Bl[r][c8 * 8] = bv;
            }
            if (ks == 0 && tid < 128) eel[tid] = ee[nt * 128 + tid];
            __syncthreads();
#pragma unroll
            for (int kk = 0; kk < 2; ++kk) {
                const half8 a0 = *(const half8*)&Al[w * 32 + lc][kk * 32 + lg * 8];
                const half8 a1 = *(const half8*)&Al[w * 32 + 16 + lc][kk * 32 + lg * 8];
#pragma unroll
                for (int cf = 0; cf < 8; ++cf) {
                    const half8 b = *(const half8*)&Bl[cf * 16 + lc][kk * 32 + lg * 8];
                    acc[0][cf] = __builtin_amdgcn_mfma_f32_16x16x32_f16(a0, b, acc[0][cf], 0, 0, 0);
                    acc[1][cf] = __builtin_amdgcn_mfma_f32_16x16x32_f16(a1, b, acc[1][cf], 0, 0, 0);
                }
            }
        }

        // ---- epilogue: d = zz + ee - 2*dot.  C frag: col = lc, row = lg*4+reg ----
        if (MODE == 0) {
#pragma unroll
            for (int fr = 0; fr < 2; ++fr)
#pragma unroll
            for (int reg = 0; reg < 4; ++reg) {
                const int rl = w * 32 + fr * 16 + lg * 4 + reg;
                const float zr = zzl[rl];
                float dv[8], mloc = 1e30f;
#pragma unroll
                for (int cf = 0; cf < 8; ++cf) {
                    const float d = fmaf(-2.0f, acc[fr][cf][reg], zr + eel[cf * 16 + lc]);
                    dv[cf] = d;
                    mloc = fminf(mloc, d);
                }
#pragma unroll
                for (int off = 1; off < 16; off <<= 1)
                    mloc = fminf(mloc, __shfl_xor(mloc, off, 64));
                const int ri = fr * 4 + reg;
                const float nM = fminf(runM[ri], mloc);
                float s = 0.0f;
#pragma unroll
                for (int cf = 0; cf < 8; ++cf) s += __expf(nM - dv[cf]);
#pragma unroll
                for (int off = 1; off < 16; off <<= 1)
                    s += __shfl_xor(s, off, 64);
                runZ[ri] = runZ[ri] * __expf(nM - runM[ri]) + s;
                runM[ri] = nM;
            }
        } else {
            float sp[8];
#pragma unroll
            for (int cf = 0; cf < 8; ++cf) sp[cf] = 0.0f;
#pragma unroll
            for (int fr = 0; fr < 2; ++fr)
#pragma unroll
            for (int reg = 0; reg < 4; ++reg) {
                const int rl = w * 32 + fr * 16 + lg * 4 + reg;
                const float m = rml[rl], iz = rizl[rl], zr = zzl[rl];
#pragma unroll
                for (int cf = 0; cf < 8; ++cf) {
                    const float d = fmaf(-2.0f, acc[fr][cf][reg], zr + eel[cf * 16 + lc]);
                    sp[cf] += __expf(m - d) * iz;
                    if (d <= m + MARGIN) {   // includes argmin: d values bitwise == sweep A
                        const int rg_ = row0 + rl;
                        const int slot = atomicAdd(&cand_cnt[rg_], 1);
                        if (slot < CAND_CAP)
                            cand_idx[rg_ * CAND_CAP + slot] = nt * 128 + cf * 16 + lc;
                    }
                }
            }
#pragma unroll
            for (int cf = 0; cf < 8; ++cf) {
                float v = sp[cf];
                v += __shfl_xor(v, 16, 64);
                v += __shfl_xor(v, 32, 64);
                if (l < 16) atomicAdd(&Sl[nt * 128 + cf * 16 + l], v);
            }
        }
    }

    if (MODE == 0) {
        if (lc == 0) {
#pragma unroll
            for (int fr = 0; fr < 2; ++fr)
#pragma unroll
            for (int reg = 0; reg < 4; ++reg) {
                const int rl = w * 32 + fr * 16 + lg * 4 + reg;
                rowM[row0 + rl] = runM[fr * 4 + reg];
                rowZ[row0 + rl] = runZ[fr * 4 + reg];
            }
        }
    } else {
        __syncthreads();
        for (int i = tid; i < NCODES; i += 256)
            Spart[(size_t)blockIdx.x * NCODES + i] = Sl[i];
    }
}

// ---------------- refine: exact fp64 argmin over candidates ----------------
// No single-address atomics: per-row dmin goes to rowD[], summed in reduce1.
__global__ __launch_bounds__(256)
void refine_kernel(const float* __restrict__ z, const float* __restrict__ emb,
                   const int* __restrict__ cand_cnt, const int* __restrict__ cand_idx,
                   float* __restrict__ out_zq, float* __restrict__ out_idx,
                   unsigned int* __restrict__ bincnt, float* __restrict__ rowD)
{
    const int tid = threadIdx.x;
    const int w = tid >> 6, l = tid & 63;
    const int row = blockIdx.x * 4 + w;
    const float4 zv = *(const float4*)(z + (size_t)row * DDIM + l * 4);
    const double z0 = zv.x, z1 = zv.y, z2 = zv.z, z3 = zv.w;
    const int craw = cand_cnt[row];
    const int cnt = craw < 1 ? 1 : (craw > CAND_CAP ? CAND_CAP : craw);
    double dmin = 1e300; int kmin = 0;
    for (int c = 0; c < cnt; ++c) {
        int k = (craw < 1) ? 0 : cand_idx[row * CAND_CAP + c];
        k &= (NCODES - 1);
        const float4 ev = *(const float4*)(emb + (size_t)k * DDIM + l * 4);
        const double t0 = z0 - ev.x, t1 = z1 - ev.y, t2 = z2 - ev.z, t3 = z3 - ev.w;
        double s = t0 * t0 + t1 * t1 + t2 * t2 + t3 * t3;
#pragma unroll
        for (int off = 1; off < 64; off <<= 1) s += __shfl_xor(s, off, 64);
        if (s < dmin || (s == dmin && k < kmin)) { dmin = s; kmin = k; }
    }
    const float4 bv = *(const float4*)(emb + (size_t)kmin * DDIM + l * 4);
    *(float4*)(out_zq + (size_t)row * DDIM + l * 4) = bv;   // z + sg(zq - z) == zq
    if (l == 0) {
        out_idx[row] = (float)kmin;
        atomicAdd(&bincnt[kmin], 1u);
        rowD[row] = (float)dmin;                             // dmin == ||z - zq||^2
    }
}

// ---------------- reductions ----------------
__global__ __launch_bounds__(256)
void reduce1_kernel(const float* __restrict__ Spart, const unsigned int* __restrict__ bincnt,
                    const float* __restrict__ rowD,
                    double* __restrict__ te, double* __restrict__ tp, double* __restrict__ tm)
{
    const int k = blockIdx.x * 256 + threadIdx.x;   // grid 16 -> k < 4096
    double s = 0.0;
    for (int wg = 0; wg < 512; ++wg) s += (double)Spart[(size_t)wg * NCODES + k];
    const double avg = s * (1.0 / 65536.0);
    te[k] = avg * log(avg + 1e-10);
    const double ap = (double)bincnt[k] * (1.0 / 65536.0);
    tp[k] = ap * log(ap + 1e-10);
    double dm = 0.0;
#pragma unroll
    for (int j = 0; j < 16; ++j) dm += (double)rowD[k * 16 + j];
    tm[k] = dm;
}

__global__ __launch_bounds__(256)
void reduce2_kernel(const double* __restrict__ te, const double* __restrict__ tp,
                    const double* __restrict__ tm, float* __restrict__ out)
{
    __shared__ double sa[256], sb[256], sc[256];
    const int tid = threadIdx.x;
    double a = 0.0, b = 0.0, c = 0.0;
    for (int i = tid; i < NCODES; i += 256) { a += te[i]; b += tp[i]; c += tm[i]; }
    sa[tid] = a; sb[tid] = b; sc[tid] = c;
    __syncthreads();
    for (int s = 128; s > 0; s >>= 1) {
        if (tid < s) { sa[tid] += sa[tid + s]; sb[tid] += sb[tid + s]; sc[tid] += sc[tid + s]; }
        __syncthreads();
    }
    if (tid == 0) {
        const double entropy    = -sa[0];
        const double diversity  = log(4096.0) - entropy;
        const double perplexity = exp(-sb[0]);
        const double mse        = sc[0] * (1.0 / 16777216.0);
        const double vq         = 1.25 * mse + 0.1 * diversity;  // 0.25*c + e + 0.1*d, c==e
        out[16777216] = (float)vq;
        out[16777217] = (float)perplexity;
        out[16842754] = (float)diversity;
    }
}

extern "C" void kernel_launch(void* const* d_in, const int* in_sizes, int n_in,
                              void* d_out, int out_size, void* d_ws, size_t ws_size,
                              hipStream_t stream)
{
    const float* z   = (const float*)d_in[0];
    const float* emb = (const float*)d_in[1];
    float* out = (float*)d_out;
    char* ws = (char*)d_ws;
    if (ws_size < (size_t)WS_END) return;   // need ~18 MB scratch

    int*          cand_cnt = (int*)(ws + WS_CANDCNT);
    unsigned int* bincnt   = (unsigned int*)(ws + WS_BINCNT);
    float*        Spart    = (float*)(ws + WS_SPART);
    _Float16*     ef16     = (_Float16*)(ws + WS_EF16);
    float*        zz       = (float*)(ws + WS_ZZ);
    float*        ee       = (float*)(ws + WS_EE);
    float*        rowM     = (float*)(ws + WS_ROWM);
    float*        rowZ     = (float*)(ws + WS_ROWZ);
    int*          cand_idx = (int*)(ws + WS_CANDIDX);
    double*       te       = (double*)(ws + WS_TE);
    double*       tp       = (double*)(ws + WS_TP);
    // aliases: dead buffers reused by later stages (stream-ordered, safe)
    float*        rowD     = rowM;                      // rowM dead after sweep<1> prologue
    double*       tm       = (double*)(ws + WS_CANDIDX); // cand_idx dead after refine

    // z_f16 (32 MB) lives in the d_out z_q region; refine overwrites it at the end.
    _Float16* zf16 = (_Float16*)d_out;

    hipMemsetAsync(d_ws, 0, WS_ZERO_END, stream);   // only cand_cnt + bincnt (278 KB)
    hipLaunchKernelGGL(prep_kernel, dim3(NROWS / 4), dim3(256), 0, stream, z, zf16, zz);
    hipLaunchKernelGGL(prep_kernel, dim3(NCODES / 4), dim3(256), 0, stream, emb, ef16, ee);
    hipLaunchKernelGGL((sweep_kernel<0>), dim3(NROWS / 128), dim3(256), 0, stream,
                       zf16, ef16, zz, ee, rowM, rowZ, Spart, cand_cnt, cand_idx);
    hipLaunchKernelGGL((sweep_kernel<1>), dim3(NROWS / 128), dim3(256), 0, stream,
                       zf16, ef16, zz, ee, rowM, rowZ, Spart, cand_cnt, cand_idx);
    hipLaunchKernelGGL(refine_kernel, dim3(NROWS / 4), dim3(256), 0, stream,
                       z, emb, cand_cnt, cand_idx, out, out + 16777218, bincnt, rowD);
    hipLaunchKernelGGL(reduce1_kernel, dim3(16), dim3(256), 0, stream, Spart, bincnt, rowD, te, tp, tm);
    hipLaunchKernelGGL(reduce2_kernel, dim3(1), dim3(256), 0, stream, te, tp, tm, out);
}

// Round 3
// 525.748 us; speedup vs baseline: 2.6860x; 1.2058x over previous
//
#include <hip/hip_runtime.h>
#include <cstdint>
#include <cstddef>

// VQ-VAE vector quantizer forward, MI355X.
// B=65536 rows, K=4096 codes, D=256.
// Outputs (flat float32): z_q_st[B*D] | vq_loss | perplexity | indices[B] | diversity_loss

#define NROWS     65536
#define NCODES    4096
#define DDIM      256
#define CAND_CAP  24
#define MARGIN    0.5f
#define NPART     64

typedef _Float16 half8 __attribute__((ext_vector_type(8)));
typedef _Float16 half4 __attribute__((ext_vector_type(4)));
typedef float    f32x4 __attribute__((ext_vector_type(4)));

// ---- workspace layout (bytes) ----
#define WS_CANDCNT  0u          // 65536*4   = 262144   (zeroed)
#define WS_BINCNT   262144u     // 4096*4    = 16384    (zeroed)
#define WS_SPARTG   278528u     // 64*4096*4 = 1048576  (zeroed; global soft partials)
#define WS_ZERO_END 1327104u
#define WS_EF16     1327104u    // 4096*256*2 = 2097152
#define WS_ZZ       3424256u    // 65536*4    = 262144
#define WS_EE       3686400u    // 4096*4     = 16384
#define WS_ROWD     3702784u    // 65536*4    = 262144
#define WS_CANDIDX  3964928u    // 65536*24*4 = 6291456 (aliased as tm[4096] dbl after refine)
#define WS_TE       10256384u   // 4096*8     = 32768
#define WS_TP       10289152u   // 4096*8     = 32768
#define WS_END      10321920u

__device__ __forceinline__ void gload_lds16(const void* g, void* lds) {
    __builtin_amdgcn_global_load_lds(
        (const __attribute__((address_space(1))) unsigned int*)g,
        (__attribute__((address_space(3))) unsigned int*)lds, 16, 0, 0);
}

// ---------------- prep: fp32 row-matrix -> fp16 copy + row norms ----------------
__global__ __launch_bounds__(256)
void prep_kernel(const float* __restrict__ src, _Float16* __restrict__ dst,
                 float* __restrict__ norms)
{
    const int tid = threadIdx.x;
    const int w = tid >> 6, l = tid & 63;
    const int row = blockIdx.x * 4 + w;
    const float4 v = *(const float4*)(src + (size_t)row * DDIM + l * 4);
    half4 h;
    h[0] = (_Float16)v.x; h[1] = (_Float16)v.y;
    h[2] = (_Float16)v.z; h[3] = (_Float16)v.w;
    *(half4*)(dst + (size_t)row * DDIM + l * 4) = h;
    double s = (double)v.x * v.x + (double)v.y * v.y
             + (double)v.z * v.z + (double)v.w * v.w;
#pragma unroll
    for (int off = 1; off < 64; off <<= 1) s += __shfl_xor(s, off, 64);
    if (l == 0) norms[row] = (float)s;
}

// ---------------- fused two-phase distance sweep ----------------
// Block: 128 rows x all 4096 codes, 4 waves (wave w owns rows w*32..+31).
// A fragments live in registers for the whole kernel (64 VGPR/lane).
// B tile: 128 codes x K=256 fp16 in 64 KB LDS, staged via global_load_lds with
// pre-swizzled source (rule #21); read side XOR-swizzled (byte ^= (row&7)<<4)
// -> conflict-free ds_read_b128.  2 barriers per nt tile.
// Phase 0: per-lane branchless flash (m, Z); one cross-lane merge at end.
// Phase 1: soft partials to 64 global partial rows + fp64-refine candidates.
__global__ __launch_bounds__(256, 2)
void sweep_fused_kernel(const _Float16* __restrict__ zf, const _Float16* __restrict__ ef,
                        const float* __restrict__ zz, const float* __restrict__ ee,
                        float* __restrict__ SpartG, int* __restrict__ cand_cnt,
                        int* __restrict__ cand_idx)
{
    __shared__ _Float16 Bl[128 * 256];   // 64 KB
    __shared__ float eel[128];

    const int tid = threadIdx.x;
    const int w = tid >> 6, l = tid & 63;
    const int lg = l >> 4, lc = l & 15;
    const int row0 = blockIdx.x * 128;

    // A fragments: row = w*32 + fr*16 + lc, k = ksl*32 + lg*8 .. +8
    half8 af[2][8];
#pragma unroll
    for (int fr = 0; fr < 2; ++fr)
#pragma unroll
        for (int ksl = 0; ksl < 8; ++ksl)
            af[fr][ksl] = *(const half8*)(zf + (size_t)(row0 + w * 32 + fr * 16 + lc) * DDIM
                                          + ksl * 32 + lg * 8);

    // ||z||^2 for the 8 rows this lane's C-fragments cover (row = w*32+fr*16+lg*4+reg)
    float zr[8];
#pragma unroll
    for (int fr = 0; fr < 2; ++fr)
#pragma unroll
        for (int reg = 0; reg < 4; ++reg)
            zr[fr * 4 + reg] = zz[row0 + w * 32 + fr * 16 + lg * 4 + reg];

    const char* efb = (const char*)ef;
    char* blb = (char*)Bl;

    float pm[8], pZ[8];
#pragma unroll
    for (int i = 0; i < 8; ++i) { pm[i] = 1e30f; pZ[i] = 0.0f; }

    for (int phase = 0; phase < 2; ++phase) {
        for (int nt = 0; nt < 32; ++nt) {
            __syncthreads();   // prior tile fully consumed before overwrite
            // stage 64 KB: LDS byte p = it*4096 + w*1024 + lane*16 (linear dest);
            // source column pre-swizzled so reads can XOR-swizzle.
#pragma unroll
            for (int it = 0; it < 16; ++it) {
                const int p = it * 4096 + w * 1024 + l * 16;
                const int brow = p >> 9;
                const int cby = (p & 511) ^ ((brow & 7) << 4);
                gload_lds16(efb + (((size_t)(nt * 128 + brow)) << 9) + cby,
                            blb + it * 4096 + w * 1024);
            }
            if (tid < 128) eel[tid] = ee[nt * 128 + tid];
            __syncthreads();

            f32x4 acc[2][8];
#pragma unroll
            for (int fr = 0; fr < 2; ++fr)
#pragma unroll
                for (int cf = 0; cf < 8; ++cf) acc[fr][cf] = (f32x4){0.f, 0.f, 0.f, 0.f};

            const char* bbase = blb + ((size_t)lc << 9);
#pragma unroll
            for (int ksl = 0; ksl < 8; ++ksl) {
                const char* bp = bbase + (((ksl * 64 + lg * 16) ^ ((lc & 7) << 4)));
#pragma unroll
                for (int cf = 0; cf < 8; ++cf) {
                    const half8 b = *(const half8*)(bp + cf * 8192);
                    acc[0][cf] = __builtin_amdgcn_mfma_f32_16x16x32_f16(af[0][ksl], b, acc[0][cf], 0, 0, 0);
                    acc[1][cf] = __builtin_amdgcn_mfma_f32_16x16x32_f16(af[1][ksl], b, acc[1][cf], 0, 0, 0);
                }
            }

            float eev[8];
#pragma unroll
            for (int cf = 0; cf < 8; ++cf) eev[cf] = eel[cf * 16 + lc];

            if (phase == 0) {
                // branchless per-lane flash over this lane's 8 codes per row
#pragma unroll
                for (int fr = 0; fr < 2; ++fr)
#pragma unroll
                for (int reg = 0; reg < 4; ++reg) {
                    const int ri = fr * 4 + reg;
                    const float zrv = zr[ri];
                    float m = pm[ri], Zv = pZ[ri];
#pragma unroll
                    for (int cf = 0; cf < 8; ++cf) {
                        const float d = fmaf(-2.0f, acc[fr][cf][reg], zrv + eev[cf]);
                        const float mn = fminf(m, d);
                        Zv = fmaf(Zv, __expf(mn - m), __expf(mn - d));
                        m = mn;
                    }
                    pm[ri] = m; pZ[ri] = Zv;
                }
            } else {
                float sp[8];
#pragma unroll
                for (int cf = 0; cf < 8; ++cf) sp[cf] = 0.0f;
#pragma unroll
                for (int fr = 0; fr < 2; ++fr)
#pragma unroll
                for (int reg = 0; reg < 4; ++reg) {
                    const int ri = fr * 4 + reg;
                    const float zrv = zr[ri];
                    const float m = pm[ri], iz = pZ[ri];   // pZ holds 1/Z in phase 1
#pragma unroll
                    for (int cf = 0; cf < 8; ++cf) {
                        const float d = fmaf(-2.0f, acc[fr][cf][reg], zrv + eev[cf]);
                        sp[cf] += __expf(m - d) * iz;
                        if (d <= m + MARGIN) {   // m is the true row-min of phase-0 d
                            const int rg_ = row0 + w * 32 + fr * 16 + lg * 4 + reg;
                            const int slot = atomicAdd(&cand_cnt[rg_], 1);
                            if (slot < CAND_CAP)
                                cand_idx[(size_t)rg_ * CAND_CAP + slot] = nt * 128 + cf * 16 + lc;
                        }
                    }
                }
#pragma unroll
                for (int cf = 0; cf < 8; ++cf) {
                    float v = sp[cf];
                    v += __shfl_xor(v, 16, 64);
                    v += __shfl_xor(v, 32, 64);
                    if (l < 16)
                        atomicAdd(&SpartG[(size_t)(blockIdx.x & (NPART - 1)) * NCODES
                                          + nt * 128 + cf * 16 + l], v);
                }
            }
        }

        if (phase == 0) {
            // merge (m,Z) across the 16 lanes (lc) sharing each row; store 1/Z
#pragma unroll
            for (int ri = 0; ri < 8; ++ri) {
                float m = pm[ri], Zv = pZ[ri];
#pragma unroll
                for (int off = 1; off < 16; off <<= 1) {
                    const float mo = __shfl_xor(m, off, 64);
                    const float Zo = __shfl_xor(Zv, off, 64);
                    const float mn = fminf(m, mo);
                    Zv = fmaf(Zv, __expf(mn - m), Zo * __expf(mn - mo));
                    m = mn;
                }
                pm[ri] = m;
                pZ[ri] = 1.0f / Zv;
            }
        }
    }
}

// ---------------- refine: exact fp64 argmin over candidates ----------------
__global__ __launch_bounds__(256)
void refine_kernel(const float* __restrict__ z, const float* __restrict__ emb,
                   const int* __restrict__ cand_cnt, const int* __restrict__ cand_idx,
                   float* __restrict__ out_zq, float* __restrict__ out_idx,
                   unsigned int* __restrict__ bincnt, float* __restrict__ rowD)
{
    const int tid = threadIdx.x;
    const int w = tid >> 6, l = tid & 63;
    const int row = blockIdx.x * 4 + w;
    const float4 zv = *(const float4*)(z + (size_t)row * DDIM + l * 4);
    const double z0 = zv.x, z1 = zv.y, z2 = zv.z, z3 = zv.w;
    const int craw = cand_cnt[row];
    const int cnt = craw < 1 ? 1 : (craw > CAND_CAP ? CAND_CAP : craw);
    double dmin = 1e300; int kmin = 0;
    for (int c = 0; c < cnt; ++c) {
        int k = (craw < 1) ? 0 : cand_idx[(size_t)row * CAND_CAP + c];
        k &= (NCODES - 1);
        const float4 ev = *(const float4*)(emb + (size_t)k * DDIM + l * 4);
        const double t0 = z0 - ev.x, t1 = z1 - ev.y, t2 = z2 - ev.z, t3 = z3 - ev.w;
        double s = t0 * t0 + t1 * t1 + t2 * t2 + t3 * t3;
#pragma unroll
        for (int off = 1; off < 64; off <<= 1) s += __shfl_xor(s, off, 64);
        if (s < dmin || (s == dmin && k < kmin)) { dmin = s; kmin = k; }
    }
    const float4 bv = *(const float4*)(emb + (size_t)kmin * DDIM + l * 4);
    *(float4*)(out_zq + (size_t)row * DDIM + l * 4) = bv;   // z + sg(zq - z) == zq
    if (l == 0) {
        out_idx[row] = (float)kmin;
        atomicAdd(&bincnt[kmin], 1u);
        rowD[row] = (float)dmin;                             // dmin == ||z - zq||^2
    }
}

// ---------------- reductions ----------------
__global__ __launch_bounds__(256)
void reduce1_kernel(const float* __restrict__ Spart, const unsigned int* __restrict__ bincnt,
                    const float* __restrict__ rowD,
                    double* __restrict__ te, double* __restrict__ tp, double* __restrict__ tm)
{
    const int k = blockIdx.x * 256 + threadIdx.x;   // grid 16 -> k < 4096
    double s = 0.0;
#pragma unroll 8
    for (int p = 0; p < NPART; ++p) s += (double)Spart[(size_t)p * NCODES + k];
    const double avg = s * (1.0 / 65536.0);
    te[k] = avg * log(avg + 1e-10);
    const double ap = (double)bincnt[k] * (1.0 / 65536.0);
    tp[k] = ap * log(ap + 1e-10);
    double dm = 0.0;
#pragma unroll
    for (int j = 0; j < 16; ++j) dm += (double)rowD[k * 16 + j];
    tm[k] = dm;
}

__global__ __launch_bounds__(256)
void reduce2_kernel(const double* __restrict__ te, const double* __restrict__ tp,
                    const double* __restrict__ tm, float* __restrict__ out)
{
    __shared__ double sa[256], sb[256], sc[256];
    const int tid = threadIdx.x;
    double a = 0.0, b = 0.0, c = 0.0;
    for (int i = tid; i < NCODES; i += 256) { a += te[i]; b += tp[i]; c += tm[i]; }
    sa[tid] = a; sb[tid] = b; sc[tid] = c;
    __syncthreads();
    for (int s = 128; s > 0; s >>= 1) {
        if (tid < s) { sa[tid] += sa[tid + s]; sb[tid] += sb[tid + s]; sc[tid] += sc[tid + s]; }
        __syncthreads();
    }
    if (tid == 0) {
        const double entropy    = -sa[0];
        const double diversity  = log(4096.0) - entropy;
        const double perplexity = exp(-sb[0]);
        const double mse        = sc[0] * (1.0 / 16777216.0);
        const double vq         = 1.25 * mse + 0.1 * diversity;  // 0.25*c + e + 0.1*d, c==e
        out[16777216] = (float)vq;
        out[16777217] = (float)perplexity;
        out[16842754] = (float)diversity;
    }
}

extern "C" void kernel_launch(void* const* d_in, const int* in_sizes, int n_in,
                              void* d_out, int out_size, void* d_ws, size_t ws_size,
                              hipStream_t stream)
{
    const float* z   = (const float*)d_in[0];
    const float* emb = (const float*)d_in[1];
    float* out = (float*)d_out;
    char* ws = (char*)d_ws;
    if (ws_size < (size_t)WS_END) return;   // need ~10.4 MB scratch

    int*          cand_cnt = (int*)(ws + WS_CANDCNT);
    unsigned int* bincnt   = (unsigned int*)(ws + WS_BINCNT);
    float*        SpartG   = (float*)(ws + WS_SPARTG);
    _Float16*     ef16     = (_Float16*)(ws + WS_EF16);
    float*        zz       = (float*)(ws + WS_ZZ);
    float*        ee       = (float*)(ws + WS_EE);
    float*        rowD     = (float*)(ws + WS_ROWD);
    int*          cand_idx = (int*)(ws + WS_CANDIDX);
    double*       te       = (double*)(ws + WS_TE);
    double*       tp       = (double*)(ws + WS_TP);
    double*       tm       = (double*)(ws + WS_CANDIDX);  // cand_idx dead after refine

    // z_f16 (32 MB) lives in the d_out z_q region; refine overwrites it at the end.
    _Float16* zf16 = (_Float16*)d_out;

    hipMemsetAsync(d_ws, 0, WS_ZERO_END, stream);   // cand_cnt + bincnt + SpartG (1.3 MB)
    hipLaunchKernelGGL(prep_kernel, dim3(NROWS / 4), dim3(256), 0, stream, z, zf16, zz);
    hipLaunchKernelGGL(prep_kernel, dim3(NCODES / 4), dim3(256), 0, stream, emb, ef16, ee);
    hipLaunchKernelGGL(sweep_fused_kernel, dim3(NROWS / 128), dim3(256), 0, stream,
                       zf16, ef16, zz, ee, SpartG, cand_cnt, cand_idx);
    hipLaunchKernelGGL(refine_kernel, dim3(NROWS / 4), dim3(256), 0, stream,
                       z, emb, cand_cnt, cand_idx, out, out + 16777218, bincnt, rowD);
    hipLaunchKernelGGL(reduce1_kernel, dim3(16), dim3(256), 0, stream, SpartG, bincnt, rowD, te, tp, tm);
    hipLaunchKernelGGL(reduce2_kernel, dim3(1), dim3(256), 0, stream, te, tp, tm, out);
}

// Round 4
// 458.980 us; speedup vs baseline: 3.0768x; 1.1455x over previous
//
#include <hip/hip_runtime.h>
#include <cstdint>
#include <cstddef>

// VQ-VAE vector quantizer forward, MI355X.
// B=65536 rows, K=4096 codes, D=256.
// Outputs (flat float32): z_q_st[B*D] | vq_loss | perplexity | indices[B] | diversity_loss

#define NROWS     65536
#define NCODES    4096
#define DDIM      256
#define CAND_CAP  24
#define MARGIN    0.5f

typedef _Float16 half8 __attribute__((ext_vector_type(8)));
typedef _Float16 half4 __attribute__((ext_vector_type(4)));
typedef float    f32x4 __attribute__((ext_vector_type(4)));

// ---- workspace layout (bytes) ----
#define WS_CANDCNT  0u          // 65536*4   = 262144   (zeroed)
#define WS_BINCNT   262144u     // 4096*4    = 16384    (zeroed)
#define WS_ZERO_END 278528u
#define WS_SPART    278528u     // 512*4096*4 = 8388608 (fully written by sweep)
#define WS_EF16     8667136u    // 4096*256*2 = 2097152
#define WS_EE       10764288u   // 4096*4     = 16384
#define WS_ROWD     10780672u   // 65536*4    = 262144
#define WS_CANDIDX  11042816u   // 65536*24*4 = 6291456 (aliased as tm[4096] dbl after refine)
#define WS_TE       17334272u   // 4096*8     = 32768
#define WS_TP       17367040u   // 4096*8     = 32768
#define WS_END      17399808u

__device__ __forceinline__ void gload_lds16(const void* g, void* lds) {
    __builtin_amdgcn_global_load_lds(
        (const __attribute__((address_space(1))) unsigned int*)g,
        (__attribute__((address_space(3))) unsigned int*)lds, 16, 0, 0);
}

// ---------------- prep (embedding only): fp32 -> fp16 copy + row norms ----------------
__global__ __launch_bounds__(256)
void prep_kernel(const float* __restrict__ src, _Float16* __restrict__ dst,
                 float* __restrict__ norms)
{
    const int tid = threadIdx.x;
    const int w = tid >> 6, l = tid & 63;
    const int row = blockIdx.x * 4 + w;
    const float4 v = *(const float4*)(src + (size_t)row * DDIM + l * 4);
    half4 h;
    h[0] = (_Float16)v.x; h[1] = (_Float16)v.y;
    h[2] = (_Float16)v.z; h[3] = (_Float16)v.w;
    *(half4*)(dst + (size_t)row * DDIM + l * 4) = h;
    double s = (double)v.x * v.x + (double)v.y * v.y
             + (double)v.z * v.z + (double)v.w * v.w;
#pragma unroll
    for (int off = 1; off < 64; off <<= 1) s += __shfl_xor(s, off, 64);
    if (l == 0) norms[row] = (float)s;
}

// ---------------- fused two-phase distance sweep, double-buffered ----------------
// Block: 128 rows x all 4096 codes, 4 waves (wave w owns rows w*32..+31).
// A fragments (fp16, converted from f32 z in-register) live in VGPRs throughout.
// B: 64-code x K=256 sub-tiles, 2 x 32 KB LDS double-buffer via global_load_lds
// with pre-swizzled source; reads XOR-swizzled (byte ^= (row&7)<<4).
// Schedule per step: STAGE(next) -> ds_read+MFMA(cur) -> epilogue -> barrier.
// Sweep runs on shifted distances d' = ||e||^2 - 2 z.e (row-shift invariant).
// Phase 0 (steps 0..63): exact online flash (m, Z) with defer-rescale.
// Phase 1 (steps 64..127): identical d'; soft partials into LDS Sl; candidates.
__global__ __launch_bounds__(256, 2)
void sweep_fused_kernel(const float* __restrict__ z, const _Float16* __restrict__ ef,
                        const float* __restrict__ ee, float* __restrict__ Spart,
                        int* __restrict__ cand_cnt, int* __restrict__ cand_idx)
{
    __shared__ _Float16 Bl[2][64 * 256];   // 2 x 32 KB
    __shared__ float Sl[NCODES];           // 16 KB soft accumulator

    const int tid = threadIdx.x;
    const int w = tid >> 6, l = tid & 63;
    const int lg = l >> 4, lc = l & 15;
    const int row0 = blockIdx.x * 128;

    // A fragments: row = w*32 + fr*16 + lc, k = ksl*32 + lg*8 .. +8 (fp32 -> fp16)
    half8 af[2][8];
#pragma unroll
    for (int fr = 0; fr < 2; ++fr)
#pragma unroll
    for (int ksl = 0; ksl < 8; ++ksl) {
        const float* zp = z + (size_t)(row0 + w * 32 + fr * 16 + lc) * DDIM + ksl * 32 + lg * 8;
        const float4 v0 = *(const float4*)zp;
        const float4 v1 = *(const float4*)(zp + 4);
        half8 h;
        h[0] = (_Float16)v0.x; h[1] = (_Float16)v0.y; h[2] = (_Float16)v0.z; h[3] = (_Float16)v0.w;
        h[4] = (_Float16)v1.x; h[5] = (_Float16)v1.y; h[6] = (_Float16)v1.z; h[7] = (_Float16)v1.w;
        af[fr][ksl] = h;
    }

    for (int i = tid; i < NCODES; i += 256) Sl[i] = 0.0f;

    // per-lane staging source offsets (constant across steps)
    int soff[8];
#pragma unroll
    for (int it = 0; it < 8; ++it) {
        const int p = w * 8192 + it * 1024 + l * 16;   // linear LDS byte within 32 KB tile
        const int brow = p >> 9;
        soff[it] = (brow << 9) + ((p & 511) ^ ((brow & 7) << 4));
    }
    const char* efb = (const char*)ef;
    char* blb = (char*)&Bl[0][0];

    float pm[8], pZ[8];
#pragma unroll
    for (int i = 0; i < 8; ++i) { pm[i] = 1e30f; pZ[i] = 0.0f; }

    // prologue: stage nt=0 into buffer 0
#pragma unroll
    for (int it = 0; it < 8; ++it)
        gload_lds16(efb + soff[it], blb + w * 8192 + it * 1024);
    __syncthreads();

    const int xorv = (lc & 7) << 4;
    const char* bRd0 = blb + (lc << 9);

    for (int s = 0; s < 128; ++s) {
        const int cur = s & 1;
        const int nt = s & 63;

        if (s < 127) {                      // stage next sub-tile into other buffer
            const int nnt = (s + 1) & 63;
            const char* src = efb + ((size_t)nnt << 15);
            char* dst = blb + (cur ^ 1) * 32768 + w * 8192;
#pragma unroll
            for (int it = 0; it < 8; ++it)
                gload_lds16(src + soff[it], dst + it * 1024);
        }

        float eev[4];
#pragma unroll
        for (int cf = 0; cf < 4; ++cf) eev[cf] = ee[nt * 64 + cf * 16 + lc];

        f32x4 acc[2][4];
#pragma unroll
        for (int fr = 0; fr < 2; ++fr)
#pragma unroll
            for (int cf = 0; cf < 4; ++cf) acc[fr][cf] = (f32x4){0.f, 0.f, 0.f, 0.f};

        const char* bb = bRd0 + cur * 32768;
#pragma unroll
        for (int ksl = 0; ksl < 8; ++ksl) {
            const int ko = (ksl * 64 + lg * 16) ^ xorv;
#pragma unroll
            for (int cf = 0; cf < 4; ++cf) {
                const half8 b = *(const half8*)(bb + cf * 8192 + ko);
                acc[0][cf] = __builtin_amdgcn_mfma_f32_16x16x32_f16(af[0][ksl], b, acc[0][cf], 0, 0, 0);
                acc[1][cf] = __builtin_amdgcn_mfma_f32_16x16x32_f16(af[1][ksl], b, acc[1][cf], 0, 0, 0);
            }
        }

        if (s < 64) {
            // phase 0: exact online flash, rescale only when the min improves
#pragma unroll
            for (int fr = 0; fr < 2; ++fr)
#pragma unroll
            for (int reg = 0; reg < 4; ++reg) {
                const int ri = fr * 4 + reg;
                const float d0 = fmaf(-2.0f, acc[fr][0][reg], eev[0]);
                const float d1 = fmaf(-2.0f, acc[fr][1][reg], eev[1]);
                const float d2 = fmaf(-2.0f, acc[fr][2][reg], eev[2]);
                const float d3 = fmaf(-2.0f, acc[fr][3][reg], eev[3]);
                const float mloc = fminf(fminf(d0, d1), fminf(d2, d3));
                float m = pm[ri];
                if (mloc < m) { pZ[ri] *= __expf(mloc - m); m = mloc; pm[ri] = m; }
                pZ[ri] += __expf(m - d0) + __expf(m - d1) + __expf(m - d2) + __expf(m - d3);
            }
        } else {
            // phase 1: d' bitwise identical to phase 0 (same regs, same ops)
            float sp[4] = {0.f, 0.f, 0.f, 0.f};
#pragma unroll
            for (int fr = 0; fr < 2; ++fr)
#pragma unroll
            for (int reg = 0; reg < 4; ++reg) {
                const int ri = fr * 4 + reg;
                const float m = pm[ri], iz = pZ[ri];   // pZ holds 1/Z in phase 1
#pragma unroll
                for (int cf = 0; cf < 4; ++cf) {
                    const float d = fmaf(-2.0f, acc[fr][cf][reg], eev[cf]);
                    sp[cf] += __expf(m - d) * iz;
                    if (d <= m + MARGIN) {   // m = exact min of phase-0 d' for this row
                        const int rg_ = row0 + w * 32 + fr * 16 + lg * 4 + reg;
                        const int slot = atomicAdd(&cand_cnt[rg_], 1);
                        if (slot < CAND_CAP)
                            cand_idx[(size_t)rg_ * CAND_CAP + slot] = nt * 64 + cf * 16 + lc;
                    }
                }
            }
#pragma unroll
            for (int cf = 0; cf < 4; ++cf) {   // row-sum across lg, then LDS accumulate
                float v = sp[cf];
                v += __shfl_xor(v, 16, 64);
                v += __shfl_xor(v, 32, 64);
                if (l < 16) atomicAdd(&Sl[nt * 64 + cf * 16 + l], v);
            }
        }

        if (s == 63) {
            // phase boundary: merge (m,Z) across the 16 lanes sharing each row; pZ := 1/Z
#pragma unroll
            for (int ri = 0; ri < 8; ++ri) {
                float m = pm[ri], Zv = pZ[ri];
#pragma unroll
                for (int off = 1; off < 16; off <<= 1) {
                    const float mo = __shfl_xor(m, off, 64);
                    const float Zo = __shfl_xor(Zv, off, 64);
                    const float mn = fminf(m, mo);
                    Zv = Zv * __expf(mn - m) + Zo * __expf(mn - mo);
                    m = mn;
                }
                pm[ri] = m;
                pZ[ri] = 1.0f / Zv;
            }
        }

        __syncthreads();   // drains stage(s+1) loads (issued a full compute phase ago)
    }

    for (int i = tid; i < NCODES; i += 256)
        Spart[(size_t)blockIdx.x * NCODES + i] = Sl[i];
}

// ---------------- refine: exact fp64 argmin over candidates ----------------
__global__ __launch_bounds__(256)
void refine_kernel(const float* __restrict__ z, const float* __restrict__ emb,
                   const int* __restrict__ cand_cnt, const int* __restrict__ cand_idx,
                   float* __restrict__ out_zq, float* __restrict__ out_idx,
                   unsigned int* __restrict__ bincnt, float* __restrict__ rowD)
{
    const int tid = threadIdx.x;
    const int w = tid >> 6, l = tid & 63;
    const int row = blockIdx.x * 4 + w;
    const float4 zv = *(const float4*)(z + (size_t)row * DDIM + l * 4);
    const double z0 = zv.x, z1 = zv.y, z2 = zv.z, z3 = zv.w;
    const int craw = cand_cnt[row];
    const int cnt = craw < 1 ? 1 : (craw > CAND_CAP ? CAND_CAP : craw);
    double dmin = 1e300; int kmin = 0;
    for (int c = 0; c < cnt; ++c) {
        int k = (craw < 1) ? 0 : cand_idx[(size_t)row * CAND_CAP + c];
        k &= (NCODES - 1);
        const float4 ev = *(const float4*)(emb + (size_t)k * DDIM + l * 4);
        const double t0 = z0 - ev.x, t1 = z1 - ev.y, t2 = z2 - ev.z, t3 = z3 - ev.w;
        double s = t0 * t0 + t1 * t1 + t2 * t2 + t3 * t3;
#pragma unroll
        for (int off = 1; off < 64; off <<= 1) s += __shfl_xor(s, off, 64);
        if (s < dmin || (s == dmin && k < kmin)) { dmin = s; kmin = k; }
    }
    const float4 bv = *(const float4*)(emb + (size_t)kmin * DDIM + l * 4);
    *(float4*)(out_zq + (size_t)row * DDIM + l * 4) = bv;   // z + sg(zq - z) == zq
    if (l == 0) {
        out_idx[row] = (float)kmin;
        atomicAdd(&bincnt[kmin], 1u);
        rowD[row] = (float)dmin;                             // dmin == ||z - zq||^2
    }
}

// ---------------- reductions ----------------
__global__ __launch_bounds__(256)
void reduce1_kernel(const float* __restrict__ Spart, const unsigned int* __restrict__ bincnt,
                    const float* __restrict__ rowD,
                    double* __restrict__ te, double* __restrict__ tp, double* __restrict__ tm)
{
    const int k = blockIdx.x * 256 + threadIdx.x;   // grid 16 -> k < 4096
    double s = 0.0;
#pragma unroll 8
    for (int wg = 0; wg < 512; ++wg) s += (double)Spart[(size_t)wg * NCODES + k];
    const double avg = s * (1.0 / 65536.0);
    te[k] = avg * log(avg + 1e-10);
    const double ap = (double)bincnt[k] * (1.0 / 65536.0);
    tp[k] = ap * log(ap + 1e-10);
    double dm = 0.0;
#pragma unroll
    for (int j = 0; j < 16; ++j) dm += (double)rowD[k * 16 + j];
    tm[k] = dm;
}

__global__ __launch_bounds__(256)
void reduce2_kernel(const double* __restrict__ te, const double* __restrict__ tp,
                    const double* __restrict__ tm, float* __restrict__ out)
{
    __shared__ double sa[256], sb[256], sc[256];
    const int tid = threadIdx.x;
    double a = 0.0, b = 0.0, c = 0.0;
    for (int i = tid; i < NCODES; i += 256) { a += te[i]; b += tp[i]; c += tm[i]; }
    sa[tid] = a; sb[tid] = b; sc[tid] = c;
    __syncthreads();
    for (int s = 128; s > 0; s >>= 1) {
        if (tid < s) { sa[tid] += sa[tid + s]; sb[tid] += sb[tid + s]; sc[tid] += sc[tid + s]; }
        __syncthreads();
    }
    if (tid == 0) {
        const double entropy    = -sa[0];
        const double diversity  = log(4096.0) - entropy;
        const double perplexity = exp(-sb[0]);
        const double mse        = sc[0] * (1.0 / 16777216.0);
        const double vq         = 1.25 * mse + 0.1 * diversity;  // 0.25*c + e + 0.1*d, c==e
        out[16777216] = (float)vq;
        out[16777217] = (float)perplexity;
        out[16842754] = (float)diversity;
    }
}

extern "C" void kernel_launch(void* const* d_in, const int* in_sizes, int n_in,
                              void* d_out, int out_size, void* d_ws, size_t ws_size,
                              hipStream_t stream)
{
    const float* z   = (const float*)d_in[0];
    const float* emb = (const float*)d_in[1];
    float* out = (float*)d_out;
    char* ws = (char*)d_ws;
    if (ws_size < (size_t)WS_END) return;   // need ~17.4 MB scratch

    int*          cand_cnt = (int*)(ws + WS_CANDCNT);
    unsigned int* bincnt   = (unsigned int*)(ws + WS_BINCNT);
    float*        Spart    = (float*)(ws + WS_SPART);
    _Float16*     ef16     = (_Float16*)(ws + WS_EF16);
    float*        ee       = (float*)(ws + WS_EE);
    float*        rowD     = (float*)(ws + WS_ROWD);
    int*          cand_idx = (int*)(ws + WS_CANDIDX);
    double*       te       = (double*)(ws + WS_TE);
    double*       tp       = (double*)(ws + WS_TP);
    double*       tm       = (double*)(ws + WS_CANDIDX);  // cand_idx dead after refine

    hipMemsetAsync(d_ws, 0, WS_ZERO_END, stream);   // cand_cnt + bincnt (278 KB)
    hipLaunchKernelGGL(prep_kernel, dim3(NCODES / 4), dim3(256), 0, stream, emb, ef16, ee);
    hipLaunchKernelGGL(sweep_fused_kernel, dim3(NROWS / 128), dim3(256), 0, stream,
                       z, ef16, ee, Spart, cand_cnt, cand_idx);
    hipLaunchKernelGGL(refine_kernel, dim3(NROWS / 4), dim3(256), 0, stream,
                       z, emb, cand_cnt, cand_idx, out, out + 16777218, bincnt, rowD);
    hipLaunchKernelGGL(reduce1_kernel, dim3(16), dim3(256), 0, stream, Spart, bincnt, rowD, te, tp, tm);
    hipLaunchKernelGGL(reduce2_kernel, dim3(1), dim3(256), 0, stream, te, tp, tm, out);
}